// Round 5
// baseline (181.698 us; speedup 1.0000x reference)
//
#include <hip/hip_runtime.h>
#include <hip/hip_bf16.h>
#include <math.h>

// Problem constants
#define B_ 4
#define NQ 5440          // 64*64 + 32*32 + 16*16 + 8*8
#define M_ROWS (B_ * NQ) // 21760
#define NH 8
#define NL 4
#define NP 4
#define HD 32

typedef __attribute__((ext_vector_type(8))) short bf16x8; // 8 bf16 (4 VGPRs)
typedef __attribute__((ext_vector_type(4))) short bf16x4; // 8 bytes
typedef __attribute__((ext_vector_type(4))) float f32x4;
typedef _Float16 f16;

static __device__ __forceinline__ unsigned short f2bf(float f) {
  union { float f; unsigned u; } v; v.f = f;
  unsigned r = (v.u + 0x7fffu + ((v.u >> 16) & 1u)) >> 16; // RNE
  return (unsigned short)r;
}

// ---------------- merged prep: fp32->bf16 of value+query + weight transpose/convert
__global__ __launch_bounds__(256) void prep_all(
    const float* __restrict__ value, const float* __restrict__ query,
    unsigned short* __restrict__ value_bf, unsigned short* __restrict__ query_bf,
    const float* __restrict__ vpw, const float* __restrict__ offw,
    const float* __restrict__ attnw, const float* __restrict__ outw,
    const float* __restrict__ offb, const float* __restrict__ attnb,
    unsigned short* __restrict__ vp_t, unsigned short* __restrict__ q_t,
    unsigned short* __restrict__ out_t, float* __restrict__ biasq, int n4) {
  int id = blockIdx.x * 256 + threadIdx.x;
  if (id < 2 * n4) { // conversion part
    const float* src; unsigned short* dst; int j;
    if (id < n4) { src = value; dst = value_bf; j = id; }
    else { src = query; dst = query_bf; j = id - n4; }
    float4 f = ((const float4*)src)[j];
    bf16x4 o;
    o[0] = (short)f2bf(f.x); o[1] = (short)f2bf(f.y);
    o[2] = (short)f2bf(f.z); o[3] = (short)f2bf(f.w);
    ((bf16x4*)dst)[j] = o;
    return;
  }
  int w = id - 2 * n4;
  if (w < 65536) {                        // vp_t[256][256]
    int n = w >> 8, k = w & 255;
    vp_t[w] = f2bf(vpw[k * 256 + n]);
  } else if (w < 163840) {                // q_t[384][256] = [off^T ; attn^T]
    int q = w - 65536; int n = q >> 8, k = q & 255;
    q_t[q] = f2bf(n < 256 ? offw[k * 256 + n] : attnw[k * 128 + (n - 256)]);
  } else if (w < 229376) {                // out_t[256][256]
    int o = w - 163840; int n = o >> 8, k = o & 255;
    out_t[o] = f2bf(outw[k * 256 + n]);
  } else if (w < 229760) {                // biasq[384]
    int j = w - 229376;
    biasq[j] = j < 256 ? offb[j] : attnb[j - 256];
  }
}

// ---------------- GEMM1+2 merged: B-tile in LDS (1 barrier), ALL 16 A-fragments
// register-prefetched BEFORE the barrier. Block = 128 M x 64 N.
// Value-proj output is written as f16 (head-major) for the fma_mix gather.
__global__ __launch_bounds__(256) void gemm12_kernel(
    const unsigned short* __restrict__ valbf, const unsigned short* __restrict__ qrybf,
    const unsigned short* __restrict__ wt_vp, const unsigned short* __restrict__ wt_q,
    const float* __restrict__ vp_b, const float* __restrict__ biasq,
    f16* __restrict__ v_h, f16* __restrict__ offaw_h) {
  __shared__ unsigned short Bs[8 * 64 * 32]; // 32 KB: 8 k-tiles of [64 n][32 k]
  const int t = threadIdx.x;
  const int lane = t & 63, wid = t >> 6;
  const int qd = lane >> 4, l16 = lane & 15;
  const int g = blockIdx.x;
  const int grp = g / 80, r = g % 80;
  int by, bx;
  if (grp < 21) { by = grp * 8 + (r & 7); bx = r >> 3; }
  else          { by = 168 + (r & 1);     bx = r >> 1; } // tail: 2 rows x 10 cols
  const int bm = by * 128;
  const bool isv = bx < 4;
  const int bn = isv ? bx * 64 : (bx - 4) * 64;
  const unsigned short* A  = isv ? valbf : qrybf;
  const unsigned short* Wt = isv ? wt_vp : wt_q;

  // stage B tile (weights) via async global->LDS
  const unsigned short* bg = Wt + (size_t)(bn + (t >> 2)) * 256 + (t & 3) * 8;
  unsigned short* bs_b = Bs + (t & 192) * 8;
#pragma unroll
  for (int j = 0; j < 8; ++j)
    __builtin_amdgcn_global_load_lds(
        (const __attribute__((address_space(1))) void*)(bg + j * 32),
        (__attribute__((address_space(3))) void*)(bs_b + j * 2048), 16, 0, 0);

  // prefetch ALL A fragments into registers (16 independent dwordx4 loads)
  const unsigned short* ar0 = A + (size_t)(bm + wid * 32 + l16) * 256 + qd * 8;
  const unsigned short* ar1 = ar0 + 16 * 256;
  bf16x8 a0[8], a1[8];
#pragma unroll
  for (int j = 0; j < 8; ++j) {
    a0[j] = *(const bf16x8*)(ar0 + j * 32);
    a1[j] = *(const bf16x8*)(ar1 + j * 32);
  }
  __syncthreads(); // drains vmcnt: B staged AND A regs resident

  f32x4 acc[2][4] = {};
#pragma unroll
  for (int j = 0; j < 8; ++j) {
    const unsigned short* bt = Bs + j * 2048 + l16 * 32 + qd * 8;
#pragma unroll
    for (int ni = 0; ni < 4; ++ni) {
      const bf16x8 bf = *(const bf16x8*)(bt + ni * 512);
      acc[0][ni] = __builtin_amdgcn_mfma_f32_16x16x32_bf16(a0[j], bf, acc[0][ni], 0, 0, 0);
      acc[1][ni] = __builtin_amdgcn_mfma_f32_16x16x32_bf16(a1[j], bf, acc[1][ni], 0, 0, 0);
    }
  }
  // C/D layout: col = lane&15, row = (lane>>4)*4 + reg [m89-verified]
  if (isv) {
#pragma unroll
    for (int ni = 0; ni < 4; ++ni) {
      const int c = bn + ni * 16 + l16;
      const float bb = vp_b[c];
      const int h = c >> 5, d = c & 31;
#pragma unroll
      for (int mi = 0; mi < 2; ++mi)
#pragma unroll
        for (int rr = 0; rr < 4; ++rr) {
          const int gm = bm + wid * 32 + mi * 16 + qd * 4 + rr;
          const int b = gm / NQ, pix = gm - b * NQ;
          v_h[((size_t)(b * NH + h) * NQ + pix) * HD + d] = (f16)(acc[mi][ni][rr] + bb);
        }
    }
  } else {
#pragma unroll
    for (int ni = 0; ni < 4; ++ni) {
      const int c = bn + ni * 16 + l16;
      const float bb = biasq[c];
#pragma unroll
      for (int mi = 0; mi < 2; ++mi)
#pragma unroll
        for (int rr = 0; rr < 4; ++rr) {
          const int gm = bm + wid * 32 + mi * 16 + qd * 4 + rr;
          offaw_h[(size_t)gm * 384 + c] = (f16)(acc[mi][ni][rr] + bb);
        }
    }
  }
}

// ---------------- Fused softmax + deformable sampling + OUTPUT PROJECTION.
// Block = 32 queries of one batch. 4x {phase A (tuples) -> phase B (gather)},
// phase B writes bf16 attn rows into XOR-swizzled LDS tile s_attn[32][256];
// epilogue does out = s_attn @ wt_out^T + out_b via MFMA (A-frags from LDS,
// B-frags streamed from L2-resident 131 KB wt_out). Kills the attn_bf
// global round-trip and the separate gemm_out dispatch.
__global__ __launch_bounds__(256) void sample_fused_kernel(
    const f16* __restrict__ v, const float* __restrict__ refp,
    const f16* __restrict__ offaw_h, const unsigned short* __restrict__ wt_out,
    const float* __restrict__ out_b, float* __restrict__ out) {
  __shared__ __align__(16) uint2 s_t[16 * 64 * 4];           // 32 KB [p][qh][c]
  __shared__ __align__(16) unsigned short s_attn[32 * 256];  // 16 KB, XOR-swizzled
  const int t = threadIdx.x;
  const int lane = t & 63, wave = t >> 6;
  // XCD swizzle: xcd = blk&7, batch = xcd>>1 (per-batch v is 2.78 MB < 4 MB L2/XCD)
  const int blk = blockIdx.x;                 // grid = 680 = 85*8
  const int b = (blk & 7) >> 1;
  const int qidx = (blk >> 3) * 2 + (blk & 1);  // 0..169
  const int q0 = b * NQ + qidx * 32;

  for (int chunk = 0; chunk < 4; ++chunk) {
    const int cq0 = q0 + chunk * 8;
    { // ---- phase A: load offsets+logits, in-wave softmax, tuple compute
      const int qh = wave * 16 + (lane >> 2);     // 64 (q,h) pairs
      const int l = lane & 3;                     // level within 4-lane group
      const int q = qh >> 3, h = qh & 7;
      const f16* row = offaw_h + (size_t)(cq0 + q) * 384;
      union { uint4 u4; f16 hh[8]; } off8;
      off8.u4 = *(const uint4*)(row + h * 32 + l * 8);
      union { uint2 u2; f16 hh[4]; } lg4;
      lg4.u2 = *(const uint2*)(row + 256 + h * 16 + l * 4);
      const float2 rxy = *(const float2*)(refp + (size_t)(cq0 + q) * 8 + l * 2);

      float lgf[4];
#pragma unroll
      for (int j = 0; j < 4; ++j) lgf[j] = (float)lg4.hh[j];
      float m = fmaxf(fmaxf(lgf[0], lgf[1]), fmaxf(lgf[2], lgf[3]));
      m = fmaxf(m, __shfl_xor(m, 1));
      m = fmaxf(m, __shfl_xor(m, 2));
      float e[4], s = 0.f;
#pragma unroll
      for (int j = 0; j < 4; ++j) { e[j] = __expf(lgf[j] - m); s += e[j]; }
      s += __shfl_xor(s, 1);
      s += __shfl_xor(s, 2);
      const float inv = 1.f / s;

      const int Wl = 64 >> l, Hl = 64 >> l;
      const int LVL_OFF = (l == 0) ? 0 : (l == 1) ? 4096 : (l == 2) ? 5120 : 5376;
      const unsigned vbase = (unsigned)(((b * NH + h) * NQ + LVL_OFF) * 64);
      const float pxb = rxy.x * (float)Wl - 0.5f;
      const float pyb = rxy.y * (float)Hl - 0.5f;
#pragma unroll
      for (int pp = 0; pp < 4; ++pp) {
        const int p = l * 4 + pp;
        const float ox = (float)off8.hh[pp * 2];
        const float oy = (float)off8.hh[pp * 2 + 1];
        const float a  = e[pp] * inv;
        const float px = pxb + ox;
        const float py = pyb + oy;
        const float x0f = floorf(px), y0f = floorf(py);
        const int x0 = (int)x0f, y0 = (int)y0f;
        const int x1 = x0 + 1, y1 = y0 + 1;
        const float wx = px - x0f, wy = py - y0f;
        const float m_x0 = (x0 >= 0 && x0 < Wl) ? 1.f : 0.f;
        const float m_x1 = (x1 >= 0 && x1 < Wl) ? 1.f : 0.f;
        const float m_y0 = (y0 >= 0 && y0 < Hl) ? 1.f : 0.f;
        const float m_y1 = (y1 >= 0 && y1 < Hl) ? 1.f : 0.f;
        const int cx0 = min(max(x0, 0), Wl - 1), cx1 = min(max(x1, 0), Wl - 1);
        const int cy0 = min(max(y0, 0), Hl - 1), cy1 = min(max(y1, 0), Hl - 1);
        const int ti = (p * 64 + qh) * 4;
        const unsigned o0 = vbase + (unsigned)((cy0 * Wl + cx0) * 64);
        const unsigned o1 = vbase + (unsigned)((cy0 * Wl + cx1) * 64);
        const unsigned o2 = vbase + (unsigned)((cy1 * Wl + cx0) * 64);
        const unsigned o3 = vbase + (unsigned)((cy1 * Wl + cx1) * 64);
        const float w0 = a * (1.f - wx) * (1.f - wy) * m_x0 * m_y0;
        const float w1 = a * wx * (1.f - wy) * m_x1 * m_y0;
        const float w2 = a * (1.f - wx) * wy * m_x0 * m_y1;
        const float w3 = a * wx * wy * m_x1 * m_y1;
        uint4 pk01, pk23;
        pk01.x = o0; pk01.y = __float_as_uint(w0);
        pk01.z = o1; pk01.w = __float_as_uint(w1);
        pk23.x = o2; pk23.y = __float_as_uint(w2);
        pk23.z = o3; pk23.w = __float_as_uint(w3);
        *(uint4*)&s_t[ti]     = pk01;
        *(uint4*)&s_t[ti + 2] = pk23;
      }
    }
    __syncthreads();
    { // ---- phase B: gather. lane = qh_lo(2b) | corner(2b) | d8(2b)
      const int qh_lo = lane >> 4;
      const int c     = (lane >> 2) & 3;
      const int d8    = lane & 3;
      const char* vL = (const char*)v + d8 * 16;

      for (int s = 0; s < 4; ++s) {
        const int tqh = wave * 16 + s * 4 + qh_lo;
        const int h = tqh & 7;
        float acc[8] = {};
#pragma unroll
        for (int p = 0; p < 16; ++p) {
          const uint2 tw = s_t[(p * 64 + tqh) * 4 + c];
          const float w = __uint_as_float(tw.y);
          union { uint4 u4; f16 hh[8]; } cc;
          cc.u4 = *(const uint4*)(vL + tw.x);
#pragma unroll
          for (int k = 0; k < 8; ++k)
            acc[k] += w * (float)cc.hh[k];   // v_fma_mix_f32
        }
#pragma unroll
        for (int k = 0; k < 8; ++k) {
          acc[k] += __shfl_xor(acc[k], 4);
          acc[k] += __shfl_xor(acc[k], 8);
        }
        if (c == 0) {
          const int q = tqh >> 3;                 // 0..7 within chunk
          const int rowm = chunk * 8 + q;         // 0..31
          bf16x8 ov;
#pragma unroll
          for (int k = 0; k < 8; ++k) ov[k] = (short)f2bf(acc[k]);
          unsigned bo = (unsigned)(rowm * 512 + h * 64 + d8 * 16);
          bo ^= (unsigned)((rowm & 7) << 4);      // bank swizzle
          *(bf16x8*)((char*)s_attn + bo) = ov;
        }
      }
    }
    __syncthreads();
  }

  // ---- epilogue: out[32 x 256] = s_attn @ wt_out[n][k] + out_b via MFMA.
  // wave owns n-cols [wave*64, wave*64+64); 2 m-tiles x 4 n-tiles.
  const int qd = lane >> 4, l16 = lane & 15;
  f32x4 acc[2][4] = {};
  const unsigned short* wb = wt_out + (size_t)(wave * 64 + l16) * 256 + qd * 8;
#pragma unroll
  for (int j = 0; j < 8; ++j) {
    bf16x8 a[2], bfr[4];
#pragma unroll
    for (int mi = 0; mi < 2; ++mi) {
      const int rowm = mi * 16 + l16;
      unsigned bo = (unsigned)(rowm * 512 + j * 64 + qd * 16);
      bo ^= (unsigned)((rowm & 7) << 4);
      a[mi] = *(const bf16x8*)((const char*)s_attn + bo);
    }
#pragma unroll
    for (int ni = 0; ni < 4; ++ni)
      bfr[ni] = *(const bf16x8*)(wb + (size_t)(ni * 16) * 256 + j * 32);
#pragma unroll
    for (int mi = 0; mi < 2; ++mi)
#pragma unroll
      for (int ni = 0; ni < 4; ++ni)
        acc[mi][ni] = __builtin_amdgcn_mfma_f32_16x16x32_bf16(a[mi], bfr[ni], acc[mi][ni], 0, 0, 0);
  }
#pragma unroll
  for (int ni = 0; ni < 4; ++ni) {
    const int n = wave * 64 + ni * 16 + l16;
    const float bb = out_b[n];
#pragma unroll
    for (int mi = 0; mi < 2; ++mi)
#pragma unroll
      for (int rr = 0; rr < 4; ++rr) {
        const int m = mi * 16 + qd * 4 + rr;
        out[(size_t)(q0 + m) * 256 + n] = acc[mi][ni][rr] + bb;
      }
  }
}

extern "C" void kernel_launch(void* const* d_in, const int* in_sizes, int n_in,
                              void* d_out, int out_size, void* d_ws, size_t ws_size,
                              hipStream_t stream) {
  const float* query        = (const float*)d_in[0];
  const float* value        = (const float*)d_in[1];
  const float* refp         = (const float*)d_in[2];
  const float* value_proj_w = (const float*)d_in[3];
  const float* value_proj_b = (const float*)d_in[4];
  const float* offsets_w    = (const float*)d_in[5];
  const float* offsets_b    = (const float*)d_in[6];
  const float* attn_w_w     = (const float*)d_in[7];
  const float* attn_w_b     = (const float*)d_in[8];
  const float* out_w        = (const float*)d_in[9];
  const float* out_b        = (const float*)d_in[10];
  float* out = (float*)d_out;

  const int M = M_ROWS; // 21760
  const size_t SZ_V   = (size_t)M * 256 * 2; // 11.1 MB
  const size_t SZ_OFF = (size_t)M * 384 * 2; // 16.7 MB
  char* w = (char*)d_ws;
  unsigned short* value_bf = (unsigned short*)w;               // consumed by gemm12
  unsigned short* query_bf = (unsigned short*)(w + SZ_V);
  f16* v_h                 = (f16*)(w + 2 * SZ_V);             // head-major f16
  f16* offaw_h             = (f16*)(w + 3 * SZ_V);
  char* wts                = w + 3 * SZ_V + SZ_OFF;
  unsigned short* wt_vp    = (unsigned short*)wts;             // 256*256
  unsigned short* wt_q     = wt_vp + 65536;                    // 384*256
  unsigned short* wt_out   = wt_q + 98304;                     // 256*256
  float* biasq             = (float*)(wt_out + 65536);         // 384

  dim3 blk(256);
  const int n4 = M * 64;
  const int prep_blocks = (2 * n4 + 229760 + 255) / 256;
  prep_all<<<prep_blocks, blk, 0, stream>>>(
      value, query, value_bf, query_bf,
      value_proj_w, offsets_w, attn_w_w, out_w, offsets_b, attn_w_b,
      wt_vp, wt_q, wt_out, biasq, n4);
  // merged value-proj (bx 0-3, head-major f16 v) + offsets/logits (bx 4-9, f16)
  gemm12_kernel<<<1700, blk, 0, stream>>>(
      value_bf, query_bf, wt_vp, wt_q, value_proj_b, biasq, v_h, offaw_h);
  // fused softmax + sampling + output projection (XCD-swizzled) -> fp32 out
  sample_fused_kernel<<<680, blk, 0, stream>>>(
      v_h, refp, offaw_h, wt_out, out_b, out);
}

// Round 6
// 177.120 us; speedup vs baseline: 1.0258x; 1.0258x over previous
//
#include <hip/hip_runtime.h>
#include <hip/hip_bf16.h>
#include <math.h>

// Problem constants
#define B_ 4
#define NQ 5440          // 64*64 + 32*32 + 16*16 + 8*8
#define M_ROWS (B_ * NQ) // 21760
#define NH 8
#define NL 4
#define NP 4
#define HD 32

typedef __attribute__((ext_vector_type(8))) short bf16x8; // 8 bf16 (4 VGPRs)
typedef __attribute__((ext_vector_type(4))) short bf16x4; // 8 bytes
typedef __attribute__((ext_vector_type(4))) float f32x4;
typedef _Float16 f16;

static __device__ __forceinline__ unsigned short f2bf(float f) {
  union { float f; unsigned u; } v; v.f = f;
  unsigned r = (v.u + 0x7fffu + ((v.u >> 16) & 1u)) >> 16; // RNE
  return (unsigned short)r;
}

// ---------------- weights-only prep: transpose/convert weights + bias concat
// (value/query conversion now happens inline in gemm12 -> 67 MB traffic gone)
__global__ __launch_bounds__(256) void prep_w(
    const float* __restrict__ vpw, const float* __restrict__ offw,
    const float* __restrict__ attnw, const float* __restrict__ outw,
    const float* __restrict__ offb, const float* __restrict__ attnb,
    unsigned short* __restrict__ vp_t, unsigned short* __restrict__ q_t,
    unsigned short* __restrict__ out_t, float* __restrict__ biasq) {
  int w = blockIdx.x * 256 + threadIdx.x;
  if (w < 65536) {                        // vp_t[256][256]
    int n = w >> 8, k = w & 255;
    vp_t[w] = f2bf(vpw[k * 256 + n]);
  } else if (w < 163840) {                // q_t[384][256] = [off^T ; attn^T]
    int q = w - 65536; int n = q >> 8, k = q & 255;
    q_t[q] = f2bf(n < 256 ? offw[k * 256 + n] : attnw[k * 128 + (n - 256)]);
  } else if (w < 229376) {                // out_t[256][256]
    int o = w - 163840; int n = o >> 8, k = o & 255;
    out_t[o] = f2bf(outw[k * 256 + n]);
  } else if (w < 229760) {                // biasq[384]
    int j = w - 229376;
    biasq[j] = j < 256 ? offb[j] : attnb[j - 256];
  }
}

// ---------------- GEMM1+2 merged: B-tile in LDS (1 barrier); A-tiles read as
// FP32 directly from the problem inputs and converted to bf16 in registers
// (bit-identical RNE to the old prep pass). Bijective XCD-chunked blockIdx
// swizzle keeps each 80-block group (8 by-rows x 10 bx sharing a 2 MB A-slice)
// on one XCD so the x4/x6 A re-reads are L2 hits.
// Block = 128 M x 64 N; wave = 32 M x 64 N via 2x4 mfma_16x16x32.
__global__ __launch_bounds__(256) void gemm12_kernel(
    const float* __restrict__ value, const float* __restrict__ query,
    const unsigned short* __restrict__ wt_vp, const unsigned short* __restrict__ wt_q,
    const float* __restrict__ vp_b, const float* __restrict__ biasq,
    f16* __restrict__ v_h, f16* __restrict__ offaw_h) {
  __shared__ unsigned short Bs[8 * 64 * 32]; // 32 KB: 8 k-tiles of [64 n][32 k]
  const int t = threadIdx.x;
  const int lane = t & 63, wid = t >> 6;
  const int qd = lane >> 4, l16 = lane & 15;
  // bijective XCD swizzle (nwg=1700, q=212, r=4): xcd<4 own 213, else 212
  const int g0 = blockIdx.x;
  const int xcd = g0 & 7, idx = g0 >> 3;
  const int g = (xcd < 4) ? xcd * 213 + idx : 852 + (xcd - 4) * 212 + idx;
  const int grp = g / 80, r = g % 80;
  int by, bx;
  if (grp < 21) { by = grp * 8 + (r & 7); bx = r >> 3; }
  else          { by = 168 + (r & 1);     bx = r >> 1; } // tail: 2 rows x 10 cols
  const int bm = by * 128;
  const bool isv = bx < 4;
  const int bn = isv ? bx * 64 : (bx - 4) * 64;
  const float* Af = isv ? value : query;
  const unsigned short* Wt = isv ? wt_vp : wt_q;

  // stage B tile (weights) via async global->LDS
  const unsigned short* bg = Wt + (size_t)(bn + (t >> 2)) * 256 + (t & 3) * 8;
  unsigned short* bs_b = Bs + (t & 192) * 8;
#pragma unroll
  for (int j = 0; j < 8; ++j)
    __builtin_amdgcn_global_load_lds(
        (const __attribute__((address_space(1))) void*)(bg + j * 32),
        (__attribute__((address_space(3))) void*)(bs_b + j * 2048), 16, 0, 0);

  // load ALL A fragments as fp32, convert to bf16 frags in registers
  const float* arf0 = Af + (size_t)(bm + wid * 32 + l16) * 256 + qd * 8;
  const float* arf1 = arf0 + 16 * 256;
  bf16x8 a0[8], a1[8];
#pragma unroll
  for (int j = 0; j < 8; ++j) {
    const float4 f0 = *(const float4*)(arf0 + j * 32);
    const float4 f1 = *(const float4*)(arf0 + j * 32 + 4);
    const float4 g0v = *(const float4*)(arf1 + j * 32);
    const float4 g1v = *(const float4*)(arf1 + j * 32 + 4);
    bf16x8 va, vb;
    va[0] = (short)f2bf(f0.x); va[1] = (short)f2bf(f0.y);
    va[2] = (short)f2bf(f0.z); va[3] = (short)f2bf(f0.w);
    va[4] = (short)f2bf(f1.x); va[5] = (short)f2bf(f1.y);
    va[6] = (short)f2bf(f1.z); va[7] = (short)f2bf(f1.w);
    vb[0] = (short)f2bf(g0v.x); vb[1] = (short)f2bf(g0v.y);
    vb[2] = (short)f2bf(g0v.z); vb[3] = (short)f2bf(g0v.w);
    vb[4] = (short)f2bf(g1v.x); vb[5] = (short)f2bf(g1v.y);
    vb[6] = (short)f2bf(g1v.z); vb[7] = (short)f2bf(g1v.w);
    a0[j] = va; a1[j] = vb;
  }
  __syncthreads(); // drains vmcnt: B staged; A frags resident

  f32x4 acc[2][4] = {};
#pragma unroll
  for (int j = 0; j < 8; ++j) {
    const unsigned short* bt = Bs + j * 2048 + l16 * 32 + qd * 8;
#pragma unroll
    for (int ni = 0; ni < 4; ++ni) {
      const bf16x8 bf = *(const bf16x8*)(bt + ni * 512);
      acc[0][ni] = __builtin_amdgcn_mfma_f32_16x16x32_bf16(a0[j], bf, acc[0][ni], 0, 0, 0);
      acc[1][ni] = __builtin_amdgcn_mfma_f32_16x16x32_bf16(a1[j], bf, acc[1][ni], 0, 0, 0);
    }
  }
  // C/D layout: col = lane&15, row = (lane>>4)*4 + reg [m89-verified]
  if (isv) {
#pragma unroll
    for (int ni = 0; ni < 4; ++ni) {
      const int c = bn + ni * 16 + l16;
      const float bb = vp_b[c];
      const int h = c >> 5, d = c & 31;
#pragma unroll
      for (int mi = 0; mi < 2; ++mi)
#pragma unroll
        for (int rr = 0; rr < 4; ++rr) {
          const int gm = bm + wid * 32 + mi * 16 + qd * 4 + rr;
          const int b = gm / NQ, pix = gm - b * NQ;
          v_h[((size_t)(b * NH + h) * NQ + pix) * HD + d] = (f16)(acc[mi][ni][rr] + bb);
        }
    }
  } else {
#pragma unroll
    for (int ni = 0; ni < 4; ++ni) {
      const int c = bn + ni * 16 + l16;
      const float bb = biasq[c];
#pragma unroll
      for (int mi = 0; mi < 2; ++mi)
#pragma unroll
        for (int rr = 0; rr < 4; ++rr) {
          const int gm = bm + wid * 32 + mi * 16 + qd * 4 + rr;
          offaw_h[(size_t)gm * 384 + c] = (f16)(acc[mi][ni][rr] + bb);
        }
    }
  }
}

// ---------------- GEMM3: out = attn_bf @ out_w^T + out_b (fp32) [R4 verbatim]
__global__ __launch_bounds__(256) void gemm_out_kernel(
    const unsigned short* __restrict__ attn_bf, const unsigned short* __restrict__ wt_out,
    const float* __restrict__ out_b, float* __restrict__ out) {
  __shared__ unsigned short Bs[8 * 64 * 32];
  const int t = threadIdx.x;
  const int lane = t & 63, wid = t >> 6;
  const int qd = lane >> 4, l16 = lane & 15;
  const int g = blockIdx.x;
  const int grp = g / 32, r = g % 32;
  int by, bx;
  if (grp < 21) { by = grp * 8 + (r & 7); bx = r >> 3; }
  else          { by = 168 + (r & 1);     bx = r >> 1; }
  const int bm = by * 128, bn = bx * 64;

  const unsigned short* bg = wt_out + (size_t)(bn + (t >> 2)) * 256 + (t & 3) * 8;
  unsigned short* bs_b = Bs + (t & 192) * 8;
#pragma unroll
  for (int j = 0; j < 8; ++j)
    __builtin_amdgcn_global_load_lds(
        (const __attribute__((address_space(1))) void*)(bg + j * 32),
        (__attribute__((address_space(3))) void*)(bs_b + j * 2048), 16, 0, 0);

  const unsigned short* ar0 = attn_bf + (size_t)(bm + wid * 32 + l16) * 256 + qd * 8;
  const unsigned short* ar1 = ar0 + 16 * 256;
  bf16x8 a0[8], a1[8];
#pragma unroll
  for (int j = 0; j < 8; ++j) {
    a0[j] = *(const bf16x8*)(ar0 + j * 32);
    a1[j] = *(const bf16x8*)(ar1 + j * 32);
  }
  __syncthreads();

  f32x4 acc[2][4] = {};
#pragma unroll
  for (int j = 0; j < 8; ++j) {
    const unsigned short* bt = Bs + j * 2048 + l16 * 32 + qd * 8;
#pragma unroll
    for (int ni = 0; ni < 4; ++ni) {
      const bf16x8 bf = *(const bf16x8*)(bt + ni * 512);
      acc[0][ni] = __builtin_amdgcn_mfma_f32_16x16x32_bf16(a0[j], bf, acc[0][ni], 0, 0, 0);
      acc[1][ni] = __builtin_amdgcn_mfma_f32_16x16x32_bf16(a1[j], bf, acc[1][ni], 0, 0, 0);
    }
  }
#pragma unroll
  for (int ni = 0; ni < 4; ++ni) {
    const int c = bn + ni * 16 + l16;
    const float bb = out_b[c];
#pragma unroll
    for (int mi = 0; mi < 2; ++mi)
#pragma unroll
      for (int rr = 0; rr < 4; ++rr) {
        const int gm = bm + wid * 32 + mi * 16 + qd * 4 + rr;
        out[(size_t)gm * 256 + c] = acc[mi][ni][rr] + bb;
      }
  }
}

// ---------------- Fused softmax + deformable sampling [R4 verbatim]
__global__ __launch_bounds__(256) void sample_fused_kernel(
    const f16* __restrict__ v, const float* __restrict__ refp,
    const f16* __restrict__ offaw_h, unsigned short* __restrict__ out) {
  __shared__ __align__(16) uint2 s_t[16 * 64 * 4]; // 32 KB [p][qh][c] = (off, w)
  const int t = threadIdx.x;
  // XCD swizzle: xcd = blk&7, batch = xcd>>1 (per-batch v is 2.78 MB < 4 MB L2/XCD)
  const int blk = blockIdx.x;
  const int b = (blk & 7) >> 1;
  const int q0loc = ((blk >> 3) * 2 + (blk & 1)) * 8;
  const int q0 = b * NQ + q0loc;

  { // ---- phase A: load offsets+logits, in-wave softmax, tuple compute
    const int lane = t & 63, wave = t >> 6;
    const int qh = wave * 16 + (lane >> 2);     // 64 (q,h) pairs
    const int l = lane & 3;                     // level within 4-lane group
    const int q = qh >> 3, h = qh & 7;
    const f16* row = offaw_h + (size_t)(q0 + q) * 384;
    union { uint4 u4; f16 hh[8]; } off8;
    off8.u4 = *(const uint4*)(row + h * 32 + l * 8);
    union { uint2 u2; f16 hh[4]; } lg4;
    lg4.u2 = *(const uint2*)(row + 256 + h * 16 + l * 4);
    const float2 rxy = *(const float2*)(refp + (size_t)(q0 + q) * 8 + l * 2);

    float lgf[4];
#pragma unroll
    for (int j = 0; j < 4; ++j) lgf[j] = (float)lg4.hh[j];
    float m = fmaxf(fmaxf(lgf[0], lgf[1]), fmaxf(lgf[2], lgf[3]));
    m = fmaxf(m, __shfl_xor(m, 1));
    m = fmaxf(m, __shfl_xor(m, 2));
    float e[4], s = 0.f;
#pragma unroll
    for (int j = 0; j < 4; ++j) { e[j] = __expf(lgf[j] - m); s += e[j]; }
    s += __shfl_xor(s, 1);
    s += __shfl_xor(s, 2);
    const float inv = 1.f / s;

    const int Wl = 64 >> l, Hl = 64 >> l;
    const int LVL_OFF = (l == 0) ? 0 : (l == 1) ? 4096 : (l == 2) ? 5120 : 5376;
    const unsigned vbase = (unsigned)(((b * NH + h) * NQ + LVL_OFF) * 64);
    const float pxb = rxy.x * (float)Wl - 0.5f;
    const float pyb = rxy.y * (float)Hl - 0.5f;
#pragma unroll
    for (int pp = 0; pp < 4; ++pp) {
      const int p = l * 4 + pp;
      const float ox = (float)off8.hh[pp * 2];
      const float oy = (float)off8.hh[pp * 2 + 1];
      const float a  = e[pp] * inv;
      const float px = pxb + ox;
      const float py = pyb + oy;
      const float x0f = floorf(px), y0f = floorf(py);
      const int x0 = (int)x0f, y0 = (int)y0f;
      const int x1 = x0 + 1, y1 = y0 + 1;
      const float wx = px - x0f, wy = py - y0f;
      const float m_x0 = (x0 >= 0 && x0 < Wl) ? 1.f : 0.f;
      const float m_x1 = (x1 >= 0 && x1 < Wl) ? 1.f : 0.f;
      const float m_y0 = (y0 >= 0 && y0 < Hl) ? 1.f : 0.f;
      const float m_y1 = (y1 >= 0 && y1 < Hl) ? 1.f : 0.f;
      const int cx0 = min(max(x0, 0), Wl - 1), cx1 = min(max(x1, 0), Wl - 1);
      const int cy0 = min(max(y0, 0), Hl - 1), cy1 = min(max(y1, 0), Hl - 1);
      const int ti = (p * 64 + qh) * 4;
      const unsigned o0 = vbase + (unsigned)((cy0 * Wl + cx0) * 64);
      const unsigned o1 = vbase + (unsigned)((cy0 * Wl + cx1) * 64);
      const unsigned o2 = vbase + (unsigned)((cy1 * Wl + cx0) * 64);
      const unsigned o3 = vbase + (unsigned)((cy1 * Wl + cx1) * 64);
      const float w0 = a * (1.f - wx) * (1.f - wy) * m_x0 * m_y0;
      const float w1 = a * wx * (1.f - wy) * m_x1 * m_y0;
      const float w2 = a * (1.f - wx) * wy * m_x0 * m_y1;
      const float w3 = a * wx * wy * m_x1 * m_y1;
      uint4 pk01, pk23;
      pk01.x = o0; pk01.y = __float_as_uint(w0);
      pk01.z = o1; pk01.w = __float_as_uint(w1);
      pk23.x = o2; pk23.y = __float_as_uint(w2);
      pk23.z = o3; pk23.w = __float_as_uint(w3);
      *(uint4*)&s_t[ti]     = pk01;
      *(uint4*)&s_t[ti + 2] = pk23;
    }
  }
  __syncthreads();
  // ---- phase B: gather. lane = qh_lo(2b) | corner(2b) | d8(2b)
  const int lane = t & 63, wave = t >> 6;
  const int qh_lo = lane >> 4;
  const int c     = (lane >> 2) & 3;
  const int d8    = lane & 3;
  const char* vL = (const char*)v + d8 * 16;  // 16 B sub-chunk of 64 B head vec

  for (int s = 0; s < 4; ++s) {
    const int tqh = wave * 16 + s * 4 + qh_lo;
    const int h = tqh & 7;
    float acc[8] = {};
#pragma unroll
    for (int p = 0; p < 16; ++p) {
      const uint2 tw = s_t[(p * 64 + tqh) * 4 + c];
      const float w = __uint_as_float(tw.y);
      union { uint4 u4; f16 hh[8]; } cc;
      cc.u4 = *(const uint4*)(vL + tw.x);
#pragma unroll
      for (int k = 0; k < 8; ++k)
        acc[k] += w * (float)cc.hh[k];   // v_fma_mix_f32
    }
    // combine the 4 corner partials (lanes differing in bits 2-3)
#pragma unroll
    for (int k = 0; k < 8; ++k) {
      acc[k] += __shfl_xor(acc[k], 4);
      acc[k] += __shfl_xor(acc[k], 8);
    }
    if (c == 0) {
      const int q = tqh >> 3;
      bf16x8 ov;
#pragma unroll
      for (int k = 0; k < 8; ++k) ov[k] = (short)f2bf(acc[k]);
      *(bf16x8*)(out + (size_t)(q0 + q) * 256 + h * HD + d8 * 8) = ov;
    }
  }
}

extern "C" void kernel_launch(void* const* d_in, const int* in_sizes, int n_in,
                              void* d_out, int out_size, void* d_ws, size_t ws_size,
                              hipStream_t stream) {
  const float* query        = (const float*)d_in[0];
  const float* value        = (const float*)d_in[1];
  const float* refp         = (const float*)d_in[2];
  const float* value_proj_w = (const float*)d_in[3];
  const float* value_proj_b = (const float*)d_in[4];
  const float* offsets_w    = (const float*)d_in[5];
  const float* offsets_b    = (const float*)d_in[6];
  const float* attn_w_w     = (const float*)d_in[7];
  const float* attn_w_b     = (const float*)d_in[8];
  const float* out_w        = (const float*)d_in[9];
  const float* out_b        = (const float*)d_in[10];
  float* out = (float*)d_out;

  const int M = M_ROWS; // 21760
  const size_t SZ_V   = (size_t)M * 256 * 2; // 11.1 MB
  const size_t SZ_OFF = (size_t)M * 384 * 2; // 16.7 MB
  char* w = (char*)d_ws;
  unsigned short* attn_bf  = (unsigned short*)w;               // sample out / gemm3 in
  f16* v_h                 = (f16*)(w + 2 * SZ_V);             // head-major f16
  f16* offaw_h             = (f16*)(w + 3 * SZ_V);
  char* wts                = w + 3 * SZ_V + SZ_OFF;
  unsigned short* wt_vp    = (unsigned short*)wts;             // 256*256
  unsigned short* wt_q     = wt_vp + 65536;                    // 384*256
  unsigned short* wt_out   = wt_q + 98304;                     // 256*256
  float* biasq             = (float*)(wt_out + 65536);         // 384

  dim3 blk(256);
  // weights-only prep: 229760 elements -> 898 blocks
  prep_w<<<898, blk, 0, stream>>>(
      value_proj_w, offsets_w, attn_w_w, out_w, offsets_b, attn_w_b,
      wt_vp, wt_q, wt_out, biasq);
  // merged value-proj (bx 0-3, head-major f16 v) + offsets/logits (bx 4-9, f16);
  // A read as fp32 with inline bf16 conversion; XCD-chunked swizzle
  gemm12_kernel<<<1700, blk, 0, stream>>>(
      value, query, wt_vp, wt_q, value_proj_b, biasq, v_h, offaw_h);
  // fused softmax + sampling (XCD-swizzled) -> bf16
  sample_fused_kernel<<<M / 8, blk, 0, stream>>>(v_h, refp, offaw_h, attn_bf);
  // output projection -> fp32 out
  gemm_out_kernel<<<680, blk, 0, stream>>>(attn_bf, wt_out, out_b, out);
}

// Round 7
// 171.265 us; speedup vs baseline: 1.0609x; 1.0342x over previous
//
#include <hip/hip_runtime.h>
#include <hip/hip_bf16.h>
#include <math.h>

// Problem constants
#define B_ 4
#define NQ 5440          // 64*64 + 32*32 + 16*16 + 8*8
#define M_ROWS (B_ * NQ) // 21760
#define NH 8
#define NL 4
#define NP 4
#define HD 32

typedef __attribute__((ext_vector_type(8))) short bf16x8; // 8 bf16 (4 VGPRs)
typedef __attribute__((ext_vector_type(4))) short bf16x4; // 8 bytes
typedef __attribute__((ext_vector_type(4))) float f32x4;
typedef _Float16 f16;

static __device__ __forceinline__ unsigned short f2bf(float f) {
  union { float f; unsigned u; } v; v.f = f;
  unsigned r = (v.u + 0x7fffu + ((v.u >> 16) & 1u)) >> 16; // RNE
  return (unsigned short)r;
}

// ---------------- merged prep: fp32->bf16 of value+query + weight transpose/convert
__global__ __launch_bounds__(256) void prep_all(
    const float* __restrict__ value, const float* __restrict__ query,
    unsigned short* __restrict__ value_bf, unsigned short* __restrict__ query_bf,
    const float* __restrict__ vpw, const float* __restrict__ offw,
    const float* __restrict__ attnw, const float* __restrict__ outw,
    const float* __restrict__ offb, const float* __restrict__ attnb,
    unsigned short* __restrict__ vp_t, unsigned short* __restrict__ q_t,
    unsigned short* __restrict__ out_t, float* __restrict__ biasq, int n4) {
  int id = blockIdx.x * 256 + threadIdx.x;
  if (id < 2 * n4) { // conversion part
    const float* src; unsigned short* dst; int j;
    if (id < n4) { src = value; dst = value_bf; j = id; }
    else { src = query; dst = query_bf; j = id - n4; }
    float4 f = ((const float4*)src)[j];
    bf16x4 o;
    o[0] = (short)f2bf(f.x); o[1] = (short)f2bf(f.y);
    o[2] = (short)f2bf(f.z); o[3] = (short)f2bf(f.w);
    ((bf16x4*)dst)[j] = o;
    return;
  }
  int w = id - 2 * n4;
  if (w < 65536) {                        // vp_t[256][256]
    int n = w >> 8, k = w & 255;
    vp_t[w] = f2bf(vpw[k * 256 + n]);
  } else if (w < 163840) {                // q_t[384][256] = [off^T ; attn^T]
    int q = w - 65536; int n = q >> 8, k = q & 255;
    q_t[q] = f2bf(n < 256 ? offw[k * 256 + n] : attnw[k * 128 + (n - 256)]);
  } else if (w < 229376) {                // out_t[256][256]
    int o = w - 163840; int n = o >> 8, k = o & 255;
    out_t[o] = f2bf(outw[k * 256 + n]);
  } else if (w < 229760) {                // biasq[384]
    int j = w - 229376;
    biasq[j] = j < 256 ? offb[j] : attnb[j - 256];
  }
}

// ---------------- GEMM1+2 merged: B-tile in LDS (1 barrier), ALL 16 A-fragments
// register-prefetched BEFORE the barrier. Block = 128 M x 64 N.
// NEW: epilogue stages the 128x64 f16 output tile in LDS (reusing Bs) and
// stores it vectorized in destination order (64/128 B contiguous chunks)
// instead of 64 scattered 2 B stores per thread.
__global__ __launch_bounds__(256) void gemm12_kernel(
    const unsigned short* __restrict__ valbf, const unsigned short* __restrict__ qrybf,
    const unsigned short* __restrict__ wt_vp, const unsigned short* __restrict__ wt_q,
    const float* __restrict__ vp_b, const float* __restrict__ biasq,
    f16* __restrict__ v_h, f16* __restrict__ offaw_h) {
  __shared__ unsigned short Bs[8 * 64 * 32]; // 32 KB: 8 k-tiles of [64 n][32 k]
  const int t = threadIdx.x;
  const int lane = t & 63, wid = t >> 6;
  const int qd = lane >> 4, l16 = lane & 15;
  const int g = blockIdx.x;
  const int grp = g / 80, r = g % 80;
  int by, bx;
  if (grp < 21) { by = grp * 8 + (r & 7); bx = r >> 3; }
  else          { by = 168 + (r & 1);     bx = r >> 1; } // tail: 2 rows x 10 cols
  const int bm = by * 128;
  const bool isv = bx < 4;
  const int bn = isv ? bx * 64 : (bx - 4) * 64;
  const unsigned short* A  = isv ? valbf : qrybf;
  const unsigned short* Wt = isv ? wt_vp : wt_q;

  // stage B tile (weights) via async global->LDS
  const unsigned short* bg = Wt + (size_t)(bn + (t >> 2)) * 256 + (t & 3) * 8;
  unsigned short* bs_b = Bs + (t & 192) * 8;
#pragma unroll
  for (int j = 0; j < 8; ++j)
    __builtin_amdgcn_global_load_lds(
        (const __attribute__((address_space(1))) void*)(bg + j * 32),
        (__attribute__((address_space(3))) void*)(bs_b + j * 2048), 16, 0, 0);

  // prefetch ALL A fragments into registers (16 independent dwordx4 loads)
  const unsigned short* ar0 = A + (size_t)(bm + wid * 32 + l16) * 256 + qd * 8;
  const unsigned short* ar1 = ar0 + 16 * 256;
  bf16x8 a0[8], a1[8];
#pragma unroll
  for (int j = 0; j < 8; ++j) {
    a0[j] = *(const bf16x8*)(ar0 + j * 32);
    a1[j] = *(const bf16x8*)(ar1 + j * 32);
  }
  __syncthreads(); // drains vmcnt: B staged AND A regs resident

  f32x4 acc[2][4] = {};
#pragma unroll
  for (int j = 0; j < 8; ++j) {
    const unsigned short* bt = Bs + j * 2048 + l16 * 32 + qd * 8;
#pragma unroll
    for (int ni = 0; ni < 4; ++ni) {
      const bf16x8 bf = *(const bf16x8*)(bt + ni * 512);
      acc[0][ni] = __builtin_amdgcn_mfma_f32_16x16x32_bf16(a0[j], bf, acc[0][ni], 0, 0, 0);
      acc[1][ni] = __builtin_amdgcn_mfma_f32_16x16x32_bf16(a1[j], bf, acc[1][ni], 0, 0, 0);
    }
  }
  __syncthreads(); // all waves done reading Bs -> safe to reuse as scratch

  // ---- epilogue: bias + f16 into swizzled LDS tile [128 r][64 c] (16 KB)
  // C/D layout: col = lane&15, row = (lane>>4)*4 + reg [m89-verified]
  char* sf = (char*)Bs;
#pragma unroll
  for (int ni = 0; ni < 4; ++ni) {
    const int c = bn + ni * 16 + l16;
    const float bb = isv ? vp_b[c] : biasq[c];
#pragma unroll
    for (int mi = 0; mi < 2; ++mi)
#pragma unroll
      for (int rr = 0; rr < 4; ++rr) {
        const int rl = wid * 32 + mi * 16 + qd * 4 + rr;     // local row
        const int cc = ni * 16 + l16;                        // local col
        const unsigned bo = (unsigned)(rl * 128 + cc * 2) ^ ((unsigned)(rl & 7) << 4);
        *(f16*)(sf + bo) = (f16)(acc[mi][ni][rr] + bb);
      }
  }
  __syncthreads();

  // ---- vectorized store in destination order: 4 iters x 256 thr x 16 B
  if (isv) {
    // dest per (row, hh): ((b*8+h)*NQ+pix)*64 B, 64 B contiguous over d
#pragma unroll
    for (int it = 0; it < 4; ++it) {
      const unsigned chunk = (unsigned)(it * 4096 + t * 16);
      const int hh  = chunk >> 13;          // 0..1 (which 32-col half)
      const int rl  = (chunk >> 6) & 127;   // local row
      const int off = chunk & 63;           // byte offset within 64 B d-row
      const unsigned so = (unsigned)(rl * 128 + hh * 64 + off) ^ ((unsigned)(rl & 7) << 4);
      const uint4 val = *(const uint4*)(sf + so);
      const int gm = bm + rl;
      const int b = gm / NQ, pix = gm - b * NQ;
      const int h = (bn >> 5) + hh;
      *(uint4*)((char*)v_h + ((size_t)((b * NH + h) * NQ + pix) * 64) + off) = val;
    }
  } else {
    // dest per row: gm*768 + bn*2 + off, 128 B contiguous
#pragma unroll
    for (int it = 0; it < 4; ++it) {
      const unsigned chunk = (unsigned)(it * 4096 + t * 16);
      const int rl  = chunk >> 7;           // local row
      const int off = chunk & 127;          // byte offset within 128 B row chunk
      const unsigned so = (unsigned)(rl * 128 + off) ^ ((unsigned)(rl & 7) << 4);
      const uint4 val = *(const uint4*)(sf + so);
      const int gm = bm + rl;
      *(uint4*)((char*)offaw_h + (size_t)gm * 768 + bn * 2 + off) = val;
    }
  }
}

// ---------------- GEMM3: out = attn_bf @ out_w^T + out_b (fp32) [R4 verbatim]
__global__ __launch_bounds__(256) void gemm_out_kernel(
    const unsigned short* __restrict__ attn_bf, const unsigned short* __restrict__ wt_out,
    const float* __restrict__ out_b, float* __restrict__ out) {
  __shared__ unsigned short Bs[8 * 64 * 32];
  const int t = threadIdx.x;
  const int lane = t & 63, wid = t >> 6;
  const int qd = lane >> 4, l16 = lane & 15;
  const int g = blockIdx.x;
  const int grp = g / 32, r = g % 32;
  int by, bx;
  if (grp < 21) { by = grp * 8 + (r & 7); bx = r >> 3; }
  else          { by = 168 + (r & 1);     bx = r >> 1; }
  const int bm = by * 128, bn = bx * 64;

  const unsigned short* bg = wt_out + (size_t)(bn + (t >> 2)) * 256 + (t & 3) * 8;
  unsigned short* bs_b = Bs + (t & 192) * 8;
#pragma unroll
  for (int j = 0; j < 8; ++j)
    __builtin_amdgcn_global_load_lds(
        (const __attribute__((address_space(1))) void*)(bg + j * 32),
        (__attribute__((address_space(3))) void*)(bs_b + j * 2048), 16, 0, 0);

  const unsigned short* ar0 = attn_bf + (size_t)(bm + wid * 32 + l16) * 256 + qd * 8;
  const unsigned short* ar1 = ar0 + 16 * 256;
  bf16x8 a0[8], a1[8];
#pragma unroll
  for (int j = 0; j < 8; ++j) {
    a0[j] = *(const bf16x8*)(ar0 + j * 32);
    a1[j] = *(const bf16x8*)(ar1 + j * 32);
  }
  __syncthreads();

  f32x4 acc[2][4] = {};
#pragma unroll
  for (int j = 0; j < 8; ++j) {
    const unsigned short* bt = Bs + j * 2048 + l16 * 32 + qd * 8;
#pragma unroll
    for (int ni = 0; ni < 4; ++ni) {
      const bf16x8 bf = *(const bf16x8*)(bt + ni * 512);
      acc[0][ni] = __builtin_amdgcn_mfma_f32_16x16x32_bf16(a0[j], bf, acc[0][ni], 0, 0, 0);
      acc[1][ni] = __builtin_amdgcn_mfma_f32_16x16x32_bf16(a1[j], bf, acc[1][ni], 0, 0, 0);
    }
  }
#pragma unroll
  for (int ni = 0; ni < 4; ++ni) {
    const int c = bn + ni * 16 + l16;
    const float bb = out_b[c];
#pragma unroll
    for (int mi = 0; mi < 2; ++mi)
#pragma unroll
      for (int rr = 0; rr < 4; ++rr) {
        const int gm = bm + wid * 32 + mi * 16 + qd * 4 + rr;
        out[(size_t)gm * 256 + c] = acc[mi][ni][rr] + bb;
      }
  }
}

// ---------------- Fused softmax + deformable sampling [R4 verbatim]
__global__ __launch_bounds__(256) void sample_fused_kernel(
    const f16* __restrict__ v, const float* __restrict__ refp,
    const f16* __restrict__ offaw_h, unsigned short* __restrict__ out) {
  __shared__ __align__(16) uint2 s_t[16 * 64 * 4]; // 32 KB [p][qh][c] = (off, w)
  const int t = threadIdx.x;
  // XCD swizzle: xcd = blk&7, batch = xcd>>1 (per-batch v is 2.78 MB < 4 MB L2/XCD)
  const int blk = blockIdx.x;
  const int b = (blk & 7) >> 1;
  const int q0loc = ((blk >> 3) * 2 + (blk & 1)) * 8;
  const int q0 = b * NQ + q0loc;

  { // ---- phase A: load offsets+logits, in-wave softmax, tuple compute
    const int lane = t & 63, wave = t >> 6;
    const int qh = wave * 16 + (lane >> 2);     // 64 (q,h) pairs
    const int l = lane & 3;                     // level within 4-lane group
    const int q = qh >> 3, h = qh & 7;
    const f16* row = offaw_h + (size_t)(q0 + q) * 384;
    union { uint4 u4; f16 hh[8]; } off8;
    off8.u4 = *(const uint4*)(row + h * 32 + l * 8);
    union { uint2 u2; f16 hh[4]; } lg4;
    lg4.u2 = *(const uint2*)(row + 256 + h * 16 + l * 4);
    const float2 rxy = *(const float2*)(refp + (size_t)(q0 + q) * 8 + l * 2);

    float lgf[4];
#pragma unroll
    for (int j = 0; j < 4; ++j) lgf[j] = (float)lg4.hh[j];
    float m = fmaxf(fmaxf(lgf[0], lgf[1]), fmaxf(lgf[2], lgf[3]));
    m = fmaxf(m, __shfl_xor(m, 1));
    m = fmaxf(m, __shfl_xor(m, 2));
    float e[4], s = 0.f;
#pragma unroll
    for (int j = 0; j < 4; ++j) { e[j] = __expf(lgf[j] - m); s += e[j]; }
    s += __shfl_xor(s, 1);
    s += __shfl_xor(s, 2);
    const float inv = 1.f / s;

    const int Wl = 64 >> l, Hl = 64 >> l;
    const int LVL_OFF = (l == 0) ? 0 : (l == 1) ? 4096 : (l == 2) ? 5120 : 5376;
    const unsigned vbase = (unsigned)(((b * NH + h) * NQ + LVL_OFF) * 64);
    const float pxb = rxy.x * (float)Wl - 0.5f;
    const float pyb = rxy.y * (float)Hl - 0.5f;
#pragma unroll
    for (int pp = 0; pp < 4; ++pp) {
      const int p = l * 4 + pp;
      const float ox = (float)off8.hh[pp * 2];
      const float oy = (float)off8.hh[pp * 2 + 1];
      const float a  = e[pp] * inv;
      const float px = pxb + ox;
      const float py = pyb + oy;
      const float x0f = floorf(px), y0f = floorf(py);
      const int x0 = (int)x0f, y0 = (int)y0f;
      const int x1 = x0 + 1, y1 = y0 + 1;
      const float wx = px - x0f, wy = py - y0f;
      const float m_x0 = (x0 >= 0 && x0 < Wl) ? 1.f : 0.f;
      const float m_x1 = (x1 >= 0 && x1 < Wl) ? 1.f : 0.f;
      const float m_y0 = (y0 >= 0 && y0 < Hl) ? 1.f : 0.f;
      const float m_y1 = (y1 >= 0 && y1 < Hl) ? 1.f : 0.f;
      const int cx0 = min(max(x0, 0), Wl - 1), cx1 = min(max(x1, 0), Wl - 1);
      const int cy0 = min(max(y0, 0), Hl - 1), cy1 = min(max(y1, 0), Hl - 1);
      const int ti = (p * 64 + qh) * 4;
      const unsigned o0 = vbase + (unsigned)((cy0 * Wl + cx0) * 64);
      const unsigned o1 = vbase + (unsigned)((cy0 * Wl + cx1) * 64);
      const unsigned o2 = vbase + (unsigned)((cy1 * Wl + cx0) * 64);
      const unsigned o3 = vbase + (unsigned)((cy1 * Wl + cx1) * 64);
      const float w0 = a * (1.f - wx) * (1.f - wy) * m_x0 * m_y0;
      const float w1 = a * wx * (1.f - wy) * m_x1 * m_y0;
      const float w2 = a * (1.f - wx) * wy * m_x0 * m_y1;
      const float w3 = a * wx * wy * m_x1 * m_y1;
      uint4 pk01, pk23;
      pk01.x = o0; pk01.y = __float_as_uint(w0);
      pk01.z = o1; pk01.w = __float_as_uint(w1);
      pk23.x = o2; pk23.y = __float_as_uint(w2);
      pk23.z = o3; pk23.w = __float_as_uint(w3);
      *(uint4*)&s_t[ti]     = pk01;
      *(uint4*)&s_t[ti + 2] = pk23;
    }
  }
  __syncthreads();
  // ---- phase B: gather. lane = qh_lo(2b) | corner(2b) | d8(2b)
  const int lane = t & 63, wave = t >> 6;
  const int qh_lo = lane >> 4;
  const int c     = (lane >> 2) & 3;
  const int d8    = lane & 3;
  const char* vL = (const char*)v + d8 * 16;  // 16 B sub-chunk of 64 B head vec

  for (int s = 0; s < 4; ++s) {
    const int tqh = wave * 16 + s * 4 + qh_lo;
    const int h = tqh & 7;
    float acc[8] = {};
#pragma unroll
    for (int p = 0; p < 16; ++p) {
      const uint2 tw = s_t[(p * 64 + tqh) * 4 + c];
      const float w = __uint_as_float(tw.y);
      union { uint4 u4; f16 hh[8]; } cc;
      cc.u4 = *(const uint4*)(vL + tw.x);
#pragma unroll
      for (int k = 0; k < 8; ++k)
        acc[k] += w * (float)cc.hh[k];   // v_fma_mix_f32
    }
    // combine the 4 corner partials (lanes differing in bits 2-3)
#pragma unroll
    for (int k = 0; k < 8; ++k) {
      acc[k] += __shfl_xor(acc[k], 4);
      acc[k] += __shfl_xor(acc[k], 8);
    }
    if (c == 0) {
      const int q = tqh >> 3;
      bf16x8 ov;
#pragma unroll
      for (int k = 0; k < 8; ++k) ov[k] = (short)f2bf(acc[k]);
      *(bf16x8*)(out + (size_t)(q0 + q) * 256 + h * HD + d8 * 8) = ov;
    }
  }
}

extern "C" void kernel_launch(void* const* d_in, const int* in_sizes, int n_in,
                              void* d_out, int out_size, void* d_ws, size_t ws_size,
                              hipStream_t stream) {
  const float* query        = (const float*)d_in[0];
  const float* value        = (const float*)d_in[1];
  const float* refp         = (const float*)d_in[2];
  const float* value_proj_w = (const float*)d_in[3];
  const float* value_proj_b = (const float*)d_in[4];
  const float* offsets_w    = (const float*)d_in[5];
  const float* offsets_b    = (const float*)d_in[6];
  const float* attn_w_w     = (const float*)d_in[7];
  const float* attn_w_b     = (const float*)d_in[8];
  const float* out_w        = (const float*)d_in[9];
  const float* out_b        = (const float*)d_in[10];
  float* out = (float*)d_out;

  const int M = M_ROWS; // 21760
  const size_t SZ_V   = (size_t)M * 256 * 2; // 11.1 MB
  const size_t SZ_OFF = (size_t)M * 384 * 2; // 16.7 MB
  char* w = (char*)d_ws;
  unsigned short* value_bf = (unsigned short*)w;               // consumed by gemm12
  unsigned short* attn_bf  = (unsigned short*)w;               // aliases value_bf
  unsigned short* query_bf = (unsigned short*)(w + SZ_V);
  f16* v_h                 = (f16*)(w + 2 * SZ_V);             // head-major f16
  f16* offaw_h             = (f16*)(w + 3 * SZ_V);
  char* wts                = w + 3 * SZ_V + SZ_OFF;
  unsigned short* wt_vp    = (unsigned short*)wts;             // 256*256
  unsigned short* wt_q     = wt_vp + 65536;                    // 384*256
  unsigned short* wt_out   = wt_q + 98304;                     // 256*256
  float* biasq             = (float*)(wt_out + 65536);         // 384

  dim3 blk(256);
  const int n4 = M * 64;
  const int prep_blocks = (2 * n4 + 229760 + 255) / 256;
  prep_all<<<prep_blocks, blk, 0, stream>>>(
      value, query, value_bf, query_bf,
      value_proj_w, offsets_w, attn_w_w, out_w, offsets_b, attn_w_b,
      wt_vp, wt_q, wt_out, biasq, n4);
  // merged value-proj (bx 0-3, head-major f16 v) + offsets/logits (bx 4-9, f16)
  gemm12_kernel<<<1700, blk, 0, stream>>>(
      value_bf, query_bf, wt_vp, wt_q, value_proj_b, biasq, v_h, offaw_h);
  // fused softmax + sampling (XCD-swizzled) -> bf16
  sample_fused_kernel<<<M / 8, blk, 0, stream>>>(v_h, refp, offaw_h, attn_bf);
  // output projection -> fp32 out
  gemm_out_kernel<<<680, blk, 0, stream>>>(attn_bf, wt_out, out_b, out);
}